// Round 1
// baseline (299.554 us; speedup 1.0000x reference)
//
#include <hip/hip_runtime.h>
#include <hip/hip_bf16.h>
#include <math.h>

// Problem constants
#define HDIM 1024
#define IDIM 4096
#define NE 8
#define NTOK 2048           // B*S = 2*1024
#define PADROWS 128         // tile-overrun padding rows

typedef __attribute__((ext_vector_type(8))) short bf16x8;
typedef __attribute__((ext_vector_type(4))) float f32x4;

__device__ __forceinline__ unsigned int f2bf(float f) {
    unsigned int u = __float_as_uint(f);
    u = (u + 0x7FFFu + ((u >> 16) & 1u)) >> 16;   // RNE
    return u;
}

// ---------------- Router: fp64 logits, argmax (first-max tie-break) -------------
__global__ __launch_bounds__(256) void router_k(const float* __restrict__ x,
                                                const float* __restrict__ rw,
                                                const float* __restrict__ rb,
                                                int* __restrict__ eidx,
                                                int* __restrict__ counts) {
    const int wave = threadIdx.x >> 6, lane = threadIdx.x & 63;
    const int t = blockIdx.x * 4 + wave;
    if (t >= NTOK) return;
    double acc[NE];
#pragma unroll
    for (int e = 0; e < NE; e++) acc[e] = 0.0;
    for (int h = lane; h < HDIM; h += 64) {
        double xv = (double)x[(size_t)t * HDIM + h];
        const float4* rwp = (const float4*)&rw[h * NE];
        float4 r0 = rwp[0], r1 = rwp[1];
        acc[0] += xv * (double)r0.x;  acc[1] += xv * (double)r0.y;
        acc[2] += xv * (double)r0.z;  acc[3] += xv * (double)r0.w;
        acc[4] += xv * (double)r1.x;  acc[5] += xv * (double)r1.y;
        acc[6] += xv * (double)r1.z;  acc[7] += xv * (double)r1.w;
    }
#pragma unroll
    for (int m = 32; m >= 1; m >>= 1) {
#pragma unroll
        for (int e = 0; e < NE; e++) acc[e] += __shfl_xor(acc[e], m);
    }
    if (lane == 0) {
        double best = acc[0] + (double)rb[0];
        int be = 0;
#pragma unroll
        for (int e = 1; e < NE; e++) {
            double v = acc[e] + (double)rb[e];
            if (v > best) { best = v; be = e; }
        }
        eidx[t] = be;
        atomicAdd(&counts[be], 1);
    }
}

// ---------------- Tiny prefix sum over 8 expert counts --------------------------
__global__ void scan_k(const int* __restrict__ counts, int* __restrict__ offsets) {
    if (threadIdx.x == 0 && blockIdx.x == 0) {
        int s = 0;
        for (int e = 0; e < NE; e++) { offsets[e] = s; s += counts[e]; }
        offsets[NE] = s;
    }
}

// ---------------- Gather: Xg[row] = bf16(x[t] + 0.1*game_emb[e]) ----------------
__global__ __launch_bounds__(256) void gather_k(const float* __restrict__ x,
                                                const float* __restrict__ gemb,
                                                const int* __restrict__ eidx,
                                                const int* __restrict__ offsets,
                                                int* __restrict__ cursors,
                                                int* __restrict__ rowmap,
                                                unsigned short* __restrict__ Xg) {
    __shared__ int srow, se;
    const int t = blockIdx.x;
    if (threadIdx.x == 0) {
        int e = eidx[t];
        int pos = atomicAdd(&cursors[e], 1);
        int row = offsets[e] + pos;
        rowmap[row] = t;
        srow = row; se = e;
    }
    __syncthreads();
    const int row = srow, e = se;
    const int c = threadIdx.x * 4;
    float4 xv = *(const float4*)&x[(size_t)t * HDIM + c];
    float4 gv = *(const float4*)&gemb[(size_t)e * HDIM + c];
    ushort4 o;
    o.x = (unsigned short)f2bf(xv.x + 0.1f * gv.x);
    o.y = (unsigned short)f2bf(xv.y + 0.1f * gv.y);
    o.z = (unsigned short)f2bf(xv.z + 0.1f * gv.z);
    o.w = (unsigned short)f2bf(xv.w + 0.1f * gv.w);
    *(ushort4*)&Xg[(size_t)row * HDIM + c] = o;
}

// ---------------- Grouped GEMM (bf16 MFMA), inline f32->bf16 B conversion -------
// A: bf16 [rows x K] row-major (gathered). B: f32 [K x Nfull] row-major per expert.
// EPI 0: Hout[row*IDIM+col] = bf16(gelu(acc + b1));  EPI 1: Yout[rowmap[row]*HDIM+col] = acc + b2.
template<int BM, int BN, int WROWS, int WCOLS, int EPI>
__global__ __launch_bounds__(256) void moe_gemm_k(
        const unsigned short* __restrict__ A, int lda, int K,
        const float* __restrict__ Bw, int ldbN, int Nfull,
        const float* __restrict__ bias,
        const int* __restrict__ offsets,
        const int* __restrict__ rowmap,
        unsigned short* __restrict__ Hout,
        float* __restrict__ Yout) {
    constexpr int BK = 64;
    constexpr int MFRAG = BM / (WROWS * 16);
    constexpr int NFRAG = BN / (WCOLS * 16);
    constexpr int ASLAB = BM * 8 + 8;    // ushorts per kb slab (+16B pad: de-conflicts kb groups)
    constexpr int BSLAB = BN * 8 + 8;
    __shared__ __align__(16) unsigned short At[8 * ASLAB];
    __shared__ __align__(16) unsigned short Bt[8 * BSLAB];

    const int e = blockIdx.z;
    const int rend = offsets[e + 1];
    const int r0 = offsets[e] + blockIdx.y * BM;
    if (r0 >= rend) return;
    const int c0 = blockIdx.x * BN;
    const float* Be = Bw + (size_t)e * K * ldbN;

    const int tid = threadIdx.x;
    const int wave = tid >> 6, lane = tid & 63;
    const int wr = (wave / WCOLS) * (MFRAG * 16);
    const int wc = (wave % WCOLS) * (NFRAG * 16);
    const int l15 = lane & 15, l4 = lane >> 4;

    f32x4 acc[MFRAG][NFRAG];
#pragma unroll
    for (int m = 0; m < MFRAG; m++)
#pragma unroll
        for (int n = 0; n < NFRAG; n++) acc[m][n] = (f32x4){0.f, 0.f, 0.f, 0.f};

    for (int k0 = 0; k0 < K; k0 += BK) {
        // ---- stage A (bf16 copy, fragment-interleaved [kb][row][8]) ----
#pragma unroll
        for (int p = 0; p < (8 * BM) / 256; p++) {
            int cid = p * 256 + tid;
            int row = cid >> 3, kb = cid & 7;
            uint4 v = *(const uint4*)&A[(size_t)(r0 + row) * lda + k0 + kb * 8];
            *(uint4*)&At[kb * ASLAB + row * 8] = v;
        }
        // ---- stage B (f32 load, cvt->bf16, [kb][col][8]) ----
#pragma unroll
        for (int p = 0; p < (8 * BN) / 256; p++) {
            int cid = p * 256 + tid;
            int col = cid % BN, kb = cid / BN;
            const float* bp = Be + (size_t)(k0 + kb * 8) * ldbN + c0 + col;
            unsigned int w[8];
#pragma unroll
            for (int j = 0; j < 8; j++) w[j] = f2bf(bp[(size_t)j * ldbN]);
            uint4 v;
            v.x = w[0] | (w[1] << 16);
            v.y = w[2] | (w[3] << 16);
            v.z = w[4] | (w[5] << 16);
            v.w = w[6] | (w[7] << 16);
            *(uint4*)&Bt[kb * BSLAB + col * 8] = v;
        }
        __syncthreads();
        // ---- MFMA over the K-step ----
#pragma unroll
        for (int kh = 0; kh < 2; kh++) {
            const int kb = kh * 4 + l4;
            bf16x8 af[MFRAG], bfr[NFRAG];
#pragma unroll
            for (int m = 0; m < MFRAG; m++)
                af[m] = *(const bf16x8*)&At[kb * ASLAB + (wr + m * 16 + l15) * 8];
#pragma unroll
            for (int n = 0; n < NFRAG; n++)
                bfr[n] = *(const bf16x8*)&Bt[kb * BSLAB + (wc + n * 16 + l15) * 8];
#pragma unroll
            for (int m = 0; m < MFRAG; m++)
#pragma unroll
                for (int n = 0; n < NFRAG; n++)
                    acc[m][n] = __builtin_amdgcn_mfma_f32_16x16x32_bf16(af[m], bfr[n], acc[m][n], 0, 0, 0);
        }
        __syncthreads();
    }

    // ---- epilogue ----
#pragma unroll
    for (int m = 0; m < MFRAG; m++) {
#pragma unroll
        for (int r = 0; r < 4; r++) {
            const int row = r0 + wr + m * 16 + l4 * 4 + r;
            if (row < rend) {
                if (EPI == 0) {
#pragma unroll
                    for (int n = 0; n < NFRAG; n++) {
                        int col = c0 + wc + n * 16 + l15;
                        float v = acc[m][n][r] + bias[(size_t)e * Nfull + col];
                        float g = 0.5f * v * (1.0f + erff(v * 0.70710678118654752f));
                        Hout[(size_t)row * IDIM + col] = (unsigned short)f2bf(g);
                    }
                } else {
                    const int t = rowmap[row];
#pragma unroll
                    for (int n = 0; n < NFRAG; n++) {
                        int col = c0 + wc + n * 16 + l15;
                        Yout[(size_t)t * HDIM + col] = acc[m][n][r] + bias[(size_t)e * Nfull + col];
                    }
                }
            }
        }
    }
}

// ---------------- launch ---------------------------------------------------------
extern "C" void kernel_launch(void* const* d_in, const int* in_sizes, int n_in,
                              void* d_out, int out_size, void* d_ws, size_t ws_size,
                              hipStream_t stream) {
    const float* x    = (const float*)d_in[0];
    const float* rw   = (const float*)d_in[1];
    const float* rb   = (const float*)d_in[2];
    const float* w1   = (const float*)d_in[3];
    const float* b1   = (const float*)d_in[4];
    const float* w2   = (const float*)d_in[5];
    const float* b2   = (const float*)d_in[6];
    const float* gemb = (const float*)d_in[7];
    float* out = (float*)d_out;

    // workspace layout (needs ~22.4 MB)
    char* ws = (char*)d_ws;
    unsigned short* Xg = (unsigned short*)ws;                       // (2048+128)*1024 bf16
    size_t off = (size_t)(NTOK + PADROWS) * HDIM * 2;
    unsigned short* Hbuf = (unsigned short*)(ws + off);             // (2048+128)*4096 bf16
    off += (size_t)(NTOK + PADROWS) * IDIM * 2;
    int* meta    = (int*)(ws + off);
    int* counts  = meta;            // 8
    int* cursors = meta + 8;        // 8
    int* offsets = meta + 16;       // 9
    int* eidx    = meta + 32;       // 2048
    int* rowmap  = meta + 32 + NTOK;

    hipMemsetAsync(counts, 0, 16 * sizeof(int), stream);   // counts + cursors
    router_k<<<NTOK / 4, 256, 0, stream>>>(x, rw, rb, eidx, counts);
    scan_k<<<1, 64, 0, stream>>>(counts, offsets);
    gather_k<<<NTOK, 256, 0, stream>>>(x, gemb, eidx, offsets, cursors, rowmap, Xg);
    // FFN1: [rows x 1024] @ w1[e] (1024x4096) -> gelu -> Hbuf (bf16)
    moe_gemm_k<128, 128, 2, 2, 0><<<dim3(IDIM / 128, 16, NE), 256, 0, stream>>>(
        Xg, HDIM, HDIM, w1, IDIM, IDIM, b1, offsets, rowmap, Hbuf, nullptr);
    // FFN2: [rows x 4096] @ w2[e] (4096x1024) + b2 -> scatter f32 out
    moe_gemm_k<128, 64, 4, 1, 1><<<dim3(HDIM / 64, 16, NE), 256, 0, stream>>>(
        Hbuf, IDIM, IDIM, w2, HDIM, HDIM, b2, offsets, rowmap, nullptr, out);
}